// Round 1
// baseline (123.006 us; speedup 1.0000x reference)
//
#include <hip/hip_runtime.h>

namespace {
constexpr int NQ     = 15;
constexpr int DIM    = 1 << NQ;    // 32768
constexpr int NNODES = 128;
constexpr int NEDGES = 1024;
constexpr int NGATES = 50;
constexpr int NTH    = 1024;       // threads per block
constexpr int NWAVES = NTH / 64;   // 16
constexpr float PI_F = 3.14159265358979323846f;
}

// Gate list hardcoded from the reference. op: 0 = RY(theta[a]) on qubit b,
// 1 = CNOT control a target b.
__constant__ unsigned char g_op[NGATES] = {
    0,0,1,0,0,1,0,0,1,0,0,1,0,0,1,0,0,1,0,0,
    1,0,0,0,1,0,0,1,0,0,1,0,0,1,0,0,1,0,0,1,
    0,0,0,0,1,0,0,1,0,0};
__constant__ unsigned char g_a[NGATES] = {
    0,1,0,2,3,3,4,5,4,6,7,7,8,9,8,10,11,11,12,13,
    8,14,15,16,1,14,15,6,16,17,9,18,19,9,19,20,2,21,22,13,
    23,24,25,26,0,27,28,14,29,30};
__constant__ unsigned char g_b[NGATES] = {
    0,1,1,2,3,2,4,5,5,6,7,6,8,9,9,10,11,10,12,13,
    9,14,1,2,2,5,6,5,9,10,10,13,14,10,2,5,5,10,13,10,
    5,10,0,5,5,10,14,10,5,10};

__global__ __launch_bounds__(NTH)
void nodenet_circuit(const float* __restrict__ X,
                     const float* __restrict__ ew,
                     const float* __restrict__ Ri,
                     const float* __restrict__ Ro,
                     const float* __restrict__ theta,
                     float* __restrict__ out)
{
    __shared__ float st[DIM];          // 128 KiB statevector
    __shared__ float Xs[NNODES * 5];   // 2.5 KiB
    __shared__ float red[NWAVES][10];
    __shared__ float rz[NWAVES][2];
    __shared__ float qc[NQ], qs[NQ];   // per-node initial RY cos/sin
    __shared__ float thc[31], ths[31]; // shared-theta cos/sin

    const int n    = blockIdx.x;
    const int tid  = threadIdx.x;
    const int lane = tid & 63;
    const int wid  = tid >> 6;

    if (tid < NNODES * 5) Xs[tid] = X[tid];
    if (tid >= 512 && tid < 512 + 31) {
        const int i = tid - 512;
        const float h = 0.5f * theta[i];
        thc[i] = cosf(h);
        ths[i] = sinf(h);
    }
    __syncthreads();

    // ---- message passing: M[n,:] = [mi(n,0..4) | mo(n,0..4) | X[n,0..4]] ----
    // thread tid == edge e.  bo[e,k] = sum_m Ro[m,e]*X[m,k], bi likewise.
    {
        float accO[5] = {0.f, 0.f, 0.f, 0.f, 0.f};
        float accI[5] = {0.f, 0.f, 0.f, 0.f, 0.f};
        #pragma unroll 4
        for (int m = 0; m < NNODES; ++m) {
            const float ro = Ro[m * NEDGES + tid];
            const float ri = Ri[m * NEDGES + tid];
            #pragma unroll
            for (int k = 0; k < 5; ++k) {
                const float x = Xs[m * 5 + k];
                accO[k] = fmaf(ro, x, accO[k]);
                accI[k] = fmaf(ri, x, accI[k]);
            }
        }
        const float w   = ew[tid];
        const float riW = Ri[n * NEDGES + tid] * w;
        const float roW = Ro[n * NEDGES + tid] * w;
        float v[10];
        #pragma unroll
        for (int k = 0; k < 5; ++k) { v[k] = riW * accO[k]; v[5 + k] = roW * accI[k]; }
        #pragma unroll
        for (int off = 32; off > 0; off >>= 1) {
            #pragma unroll
            for (int k = 0; k < 10; ++k) v[k] += __shfl_down(v[k], off, 64);
        }
        if (lane == 0) {
            #pragma unroll
            for (int k = 0; k < 10; ++k) red[wid][k] = v[k];
        }
    }
    __syncthreads();
    if (tid < NQ) {
        float ang;
        if (tid < 10) {
            float s = 0.f;
            for (int i = 0; i < NWAVES; ++i) s += red[i][tid];
            ang = s;
        } else {
            ang = Xs[n * 5 + (tid - 10)];
        }
        const float h = 0.5f * ang;
        qc[tid] = cosf(h);
        qs[tid] = sinf(h);
    }
    __syncthreads();

    // ---- initial product state: 15 RY gates on |0> collapsed ----
    #pragma unroll
    for (int k = 0; k < DIM / NTH; ++k) {
        const int idx = tid + k * NTH;
        float a = 1.f;
        #pragma unroll
        for (int q = 0; q < NQ; ++q)
            a *= ((idx >> (NQ - 1 - q)) & 1) ? qs[q] : qc[q];
        st[idx] = a;
    }
    __syncthreads();

    // ---- 50 gates in LDS ----
    for (int g = 0; g < NGATES; ++g) {
        if (g_op[g] == 0) {
            const int p = NQ - 1 - (int)g_b[g];
            const int S = 1 << p;
            const float c = thc[g_a[g]];
            const float s = ths[g_a[g]];
            #pragma unroll
            for (int j0 = 0; j0 < DIM / 2; j0 += NTH) {
                const int j  = j0 + tid;
                const int i0 = ((j & ~(S - 1)) << 1) | (j & (S - 1));
                const float a0 = st[i0];
                const float a1 = st[i0 + S];
                st[i0]     = c * a0 - s * a1;
                st[i0 + S] = s * a0 + c * a1;
            }
        } else {
            const int pc = NQ - 1 - (int)g_a[g];
            const int pt = NQ - 1 - (int)g_b[g];
            const int lo = pc < pt ? pc : pt;
            const int hi = pc < pt ? pt : pc;
            #pragma unroll
            for (int j0 = 0; j0 < DIM / 4; j0 += NTH) {
                const int j = j0 + tid;
                int i = ((j >> lo) << (lo + 1)) | (j & ((1 << lo) - 1));
                i = ((i >> hi) << (hi + 1)) | (i & ((1 << hi) - 1));
                i |= (1 << pc);              // control bit = 1 subspace
                const int ip = i | (1 << pt);
                const float t0 = st[i];
                const float t1 = st[ip];
                st[i]  = t1;
                st[ip] = t0;
            }
        }
        __syncthreads();
    }

    // ---- <Z_5> (bit 9) and <Z_10> (bit 4) ----
    float z5 = 0.f, z10 = 0.f;
    #pragma unroll
    for (int k = 0; k < DIM / NTH; ++k) {
        const int idx = tid + k * NTH;
        const float a = st[idx];
        const float p = a * a;
        z5  += ((idx >> 9) & 1) ? -p : p;
        z10 += ((idx >> 4) & 1) ? -p : p;
    }
    #pragma unroll
    for (int off = 32; off > 0; off >>= 1) {
        z5  += __shfl_down(z5,  off, 64);
        z10 += __shfl_down(z10, off, 64);
    }
    if (lane == 0) { rz[wid][0] = z5; rz[wid][1] = z10; }
    __syncthreads();
    if (tid == 0) {
        float a = 0.f, b = 0.f;
        for (int i = 0; i < NWAVES; ++i) { a += rz[i][0]; b += rz[i][1]; }
        out[n * 2 + 0] = PI_F * (1.f - a);
        out[n * 2 + 1] = PI_F * (1.f - b);
    }
}

extern "C" void kernel_launch(void* const* d_in, const int* in_sizes, int n_in,
                              void* d_out, int out_size, void* d_ws, size_t ws_size,
                              hipStream_t stream) {
    (void)in_sizes; (void)n_in; (void)d_ws; (void)ws_size; (void)out_size;
    const float* X     = (const float*)d_in[0];
    const float* ew    = (const float*)d_in[1];
    const float* Ri    = (const float*)d_in[2];
    const float* Ro    = (const float*)d_in[3];
    const float* theta = (const float*)d_in[4];
    float* out = (float*)d_out;

    nodenet_circuit<<<NNODES, NTH, 0, stream>>>(X, ew, Ri, Ro, theta, out);
}

// Round 3
// 15.039 us; speedup vs baseline: 8.1788x; 8.1788x over previous
//
#include <hip/hip_runtime.h>

namespace {
constexpr int NNODES = 128;
constexpr int NEDGES = 1024;
constexpr float PI_F = 3.14159265358979323846f;
}

// ---------------------------------------------------------------------------
// Kernel 1: bo[e,k] = sum_m Ro[m,e]*X[m,k], bi[e,k] = sum_m Ri[m,e]*X[m,k]
// ws layout: bw[k*1024 + e], k=0..4 -> bo, k=5..9 -> bi
// ---------------------------------------------------------------------------
__global__ __launch_bounds__(256)
void compute_b(const float* __restrict__ X,
               const float* __restrict__ Ri,
               const float* __restrict__ Ro,
               float* __restrict__ bw)
{
    __shared__ float Xs[NNODES * 5];
    __shared__ float ps[8][32][10];
    const int tid = threadIdx.x;
    for (int i = tid; i < NNODES * 5; i += 256) Xs[i] = X[i];
    __syncthreads();

    const int el = tid & 31;        // edge within block's 32-edge strip
    const int mg = tid >> 5;        // m-group 0..7 (16 nodes each)
    const int e  = blockIdx.x * 32 + el;

    float accO[5] = {0.f,0.f,0.f,0.f,0.f};
    float accI[5] = {0.f,0.f,0.f,0.f,0.f};
    for (int m = mg * 16; m < mg * 16 + 16; ++m) {
        const float ro = Ro[m * NEDGES + e];
        const float ri = Ri[m * NEDGES + e];
        #pragma unroll
        for (int k = 0; k < 5; ++k) {
            const float x = Xs[m * 5 + k];
            accO[k] = fmaf(ro, x, accO[k]);
            accI[k] = fmaf(ri, x, accI[k]);
        }
    }
    #pragma unroll
    for (int k = 0; k < 5; ++k) { ps[mg][el][k] = accO[k]; ps[mg][el][5 + k] = accI[k]; }
    __syncthreads();

    // 320 outputs (32 edges x 10 k) with 256 threads -> loop (round-2 bugfix)
    for (int i = tid; i < 320; i += 256) {
        const int el2 = i / 10, k = i % 10;
        float s = 0.f;
        #pragma unroll
        for (int g = 0; g < 8; ++g) s += ps[g][el2][k];
        bw[k * NEDGES + blockIdx.x * 32 + el2] = s;
    }
}

// ---------------------------------------------------------------------------
// Kernel 2: per node, reduce edges -> angles M[15], then simulate the two
// disconnected sub-circuits: A on qubits {0..7} (256 amps: 4 regs x 64 lanes),
// B on qubits {8,9,10,11,13,14} (64 amps: 1 reg x 64 lanes). Qubit 12 is
// unentangled & unmeasured -> dropped.
// A bit map: reg bit0=q0, reg bit1=q1, lane bit (q-2) = qubit q (q=2..7).
// B bit map: lane bits {0,1,2,3,4,5} = qubits {8,9,10,11,13,14}.
// ---------------------------------------------------------------------------
__global__ __launch_bounds__(256)
void node_circuit(const float* __restrict__ X,
                  const float* __restrict__ ew,
                  const float* __restrict__ Ri,
                  const float* __restrict__ Ro,
                  const float* __restrict__ theta,
                  const float* __restrict__ bw,
                  float* __restrict__ out)
{
    __shared__ float sred[4][10];
    const int n = blockIdx.x, tid = threadIdx.x;
    const int lane = tid & 63, wid = tid >> 6;

    // ---- mi[k] = sum_e Ri[n,e]*w[e]*bo[e,k]; mo[k] = sum_e Ro[n,e]*w[e]*bi[e,k]
    float acc[10];
    #pragma unroll
    for (int k = 0; k < 10; ++k) acc[k] = 0.f;
    #pragma unroll
    for (int it = 0; it < 4; ++it) {
        const int e = tid + it * 256;
        const float w   = ew[e];
        const float riw = Ri[n * NEDGES + e] * w;
        const float row = Ro[n * NEDGES + e] * w;
        #pragma unroll
        for (int k = 0; k < 5; ++k) {
            acc[k]     = fmaf(riw, bw[k * NEDGES + e],       acc[k]);
            acc[5 + k] = fmaf(row, bw[(5 + k) * NEDGES + e], acc[5 + k]);
        }
    }
    #pragma unroll
    for (int m = 1; m < 64; m <<= 1) {
        #pragma unroll
        for (int k = 0; k < 10; ++k) acc[k] += __shfl_xor(acc[k], m, 64);
    }
    if (lane == 0) {
        #pragma unroll
        for (int k = 0; k < 10; ++k) sred[wid][k] = acc[k];
    }
    __syncthreads();
    if (wid != 0) return;

    // ---- angles M[15] = [mi(5) | mo(5) | X(5)]
    float M[15];
    #pragma unroll
    for (int k = 0; k < 10; ++k) M[k] = sred[0][k] + sred[1][k] + sred[2][k] + sred[3][k];
    #pragma unroll
    for (int k = 0; k < 5; ++k) M[10 + k] = X[n * 5 + k];

    float ic[15], is[15];
    #pragma unroll
    for (int q = 0; q < 15; ++q) __sincosf(0.5f * M[q], &is[q], &ic[q]);

    // ---- init product states
    float lp = 1.f;
    #pragma unroll
    for (int q = 2; q < 8; ++q) lp *= ((lane >> (q - 2)) & 1) ? is[q] : ic[q];
    float r0 = lp * ic[0] * ic[1];
    float r1 = lp * is[0] * ic[1];
    float r2 = lp * ic[0] * is[1];
    float r3 = lp * is[0] * is[1];

    float b = ((lane >> 0) & 1) ? is[8]  : ic[8];
    b      *= ((lane >> 1) & 1) ? is[9]  : ic[9];
    b      *= ((lane >> 2) & 1) ? is[10] : ic[10];
    b      *= ((lane >> 3) & 1) ? is[11] : ic[11];
    b      *= ((lane >> 4) & 1) ? is[13] : ic[13];
    b      *= ((lane >> 5) & 1) ? is[14] : ic[14];

    float c_, s_, t_, v0, v1, v2, v3;
#define CS(i)        __sincosf(0.5f * theta[i], &s_, &c_)
#define RY_REG0      { t_ = r0; r0 = c_*t_ - s_*r1; r1 = fmaf(s_, t_, c_*r1); \
                       t_ = r2; r2 = c_*t_ - s_*r3; r3 = fmaf(s_, t_, c_*r3); }
#define RY_REG1      { t_ = r0; r0 = c_*t_ - s_*r2; r2 = fmaf(s_, t_, c_*r2); \
                       t_ = r1; r1 = c_*t_ - s_*r3; r3 = fmaf(s_, t_, c_*r3); }
#define RY_LANE_A(sh){ const float sg = ((lane >> (sh)) & 1) ? s_ : -s_;      \
                       v0 = __shfl_xor(r0, 1 << (sh), 64);                    \
                       v1 = __shfl_xor(r1, 1 << (sh), 64);                    \
                       v2 = __shfl_xor(r2, 1 << (sh), 64);                    \
                       v3 = __shfl_xor(r3, 1 << (sh), 64);                    \
                       r0 = fmaf(c_, r0, sg*v0); r1 = fmaf(c_, r1, sg*v1);    \
                       r2 = fmaf(c_, r2, sg*v2); r3 = fmaf(c_, r3, sg*v3); }
#define CX_LL_A(csh, tsh) { const bool p = (lane >> (csh)) & 1;               \
                       v0 = __shfl_xor(r0, 1 << (tsh), 64);                   \
                       v1 = __shfl_xor(r1, 1 << (tsh), 64);                   \
                       v2 = __shfl_xor(r2, 1 << (tsh), 64);                   \
                       v3 = __shfl_xor(r3, 1 << (tsh), 64);                   \
                       if (p) { r0 = v0; r1 = v1; r2 = v2; r3 = v3; } }
#define RY_B(sh)     { const float sg = ((lane >> (sh)) & 1) ? s_ : -s_;      \
                       v0 = __shfl_xor(b, 1 << (sh), 64);                     \
                       b = fmaf(c_, b, sg*v0); }
#define CX_B(csh, tsh) { v0 = __shfl_xor(b, 1 << (tsh), 64);                  \
                       if ((lane >> (csh)) & 1) b = v0; }

    // ---- circuit A (order preserved from GATES, qubits {0..7}) ----
    CS(0);  RY_REG0;                     // R t0 q0
    CS(1);  RY_REG1;                     // R t1 q1
    t_ = r1; r1 = r3; r3 = t_;           // C(0->1): ctrl reg0, tgt reg1
    CS(2);  RY_LANE_A(0);                // R t2 q2
    CS(3);  RY_LANE_A(1);                // R t3 q3
    CX_LL_A(1, 0);                       // C(3->2)
    CS(4);  RY_LANE_A(2);                // R t4 q4
    CS(5);  RY_LANE_A(3);                // R t5 q5
    CX_LL_A(2, 3);                       // C(4->5)
    CS(6);  RY_LANE_A(4);                // R t6 q6
    CS(7);  RY_LANE_A(5);                // R t7 q7
    CX_LL_A(5, 4);                       // C(7->6)
    CS(15); RY_REG1;                     // R t15 q1
    CS(16); RY_LANE_A(0);                // R t16 q2
    r2 = __shfl_xor(r2, 1, 64);          // C(1->2): ctrl reg1 (r2,r3), tgt lane0
    r3 = __shfl_xor(r3, 1, 64);
    CS(14); RY_LANE_A(3);                // R t14 q5
    CS(15); RY_LANE_A(4);                // R t15 q6
    CX_LL_A(4, 3);                       // C(6->5)
    CS(19); RY_LANE_A(0);                // R t19 q2
    CS(20); RY_LANE_A(3);                // R t20 q5
    CX_LL_A(0, 3);                       // C(2->5)
    CS(23); RY_LANE_A(3);                // R t23 q5
    CS(25); RY_REG0;                     // R t25 q0
    CS(26); RY_LANE_A(3);                // R t26 q5
    r1 = __shfl_xor(r1, 8, 64);          // C(0->5): ctrl reg0 (r1,r3), tgt lane3
    r3 = __shfl_xor(r3, 8, 64);
    CS(29); RY_LANE_A(3);                // R t29 q5

    // ---- circuit B (qubits {8,9,10,11,13,14} -> lane bits {0,1,2,3,4,5}) ----
    CS(8);  RY_B(0);                     // R t8  q8
    CS(9);  RY_B(1);                     // R t9  q9
    CX_B(0, 1);                          // C(8->9)
    CS(10); RY_B(2);                     // R t10 q10
    CS(11); RY_B(3);                     // R t11 q11
    CX_B(3, 2);                          // C(11->10)
    CS(13); RY_B(4);                     // R t13 q13
    CX_B(0, 1);                          // C(8->9)
    CS(14); RY_B(5);                     // R t14 q14
    CS(16); RY_B(1);                     // R t16 q9
    CS(17); RY_B(2);                     // R t17 q10
    CX_B(1, 2);                          // C(9->10)
    CS(18); RY_B(4);                     // R t18 q13
    CS(19); RY_B(5);                     // R t19 q14
    CX_B(1, 2);                          // C(9->10)
    CS(21); RY_B(2);                     // R t21 q10
    CS(22); RY_B(4);                     // R t22 q13
    CX_B(4, 2);                          // C(13->10)
    CS(24); RY_B(2);                     // R t24 q10
    CS(27); RY_B(2);                     // R t27 q10
    CS(28); RY_B(5);                     // R t28 q14
    CX_B(5, 2);                          // C(14->10)
    CS(30); RY_B(2);                     // R t30 q10

    // ---- measurement: z5 from A (lane bit 3), z10 from B (lane bit 2) ----
    float zA = (r0*r0 + r1*r1 + r2*r2 + r3*r3) * (((lane >> 3) & 1) ? -1.f : 1.f);
    float zB = (b*b)                            * (((lane >> 2) & 1) ? -1.f : 1.f);
    #pragma unroll
    for (int m = 1; m < 64; m <<= 1) {
        zA += __shfl_xor(zA, m, 64);
        zB += __shfl_xor(zB, m, 64);
    }
    if (lane == 0) {
        out[n * 2 + 0] = PI_F * (1.f - zA);
        out[n * 2 + 1] = PI_F * (1.f - zB);
    }
#undef CS
#undef RY_REG0
#undef RY_REG1
#undef RY_LANE_A
#undef CX_LL_A
#undef RY_B
#undef CX_B
}

extern "C" void kernel_launch(void* const* d_in, const int* in_sizes, int n_in,
                              void* d_out, int out_size, void* d_ws, size_t ws_size,
                              hipStream_t stream) {
    (void)in_sizes; (void)n_in; (void)ws_size; (void)out_size;
    const float* X     = (const float*)d_in[0];
    const float* ew    = (const float*)d_in[1];
    const float* Ri    = (const float*)d_in[2];
    const float* Ro    = (const float*)d_in[3];
    const float* theta = (const float*)d_in[4];
    float* out = (float*)d_out;
    float* bw  = (float*)d_ws;   // 10 * 1024 floats = 40 KiB

    compute_b<<<32, 256, 0, stream>>>(X, Ri, Ro, bw);
    node_circuit<<<NNODES, 256, 0, stream>>>(X, ew, Ri, Ro, theta, bw, out);
}

// Round 4
// 12.875 us; speedup vs baseline: 9.5538x; 1.1681x over previous
//
#include <hip/hip_runtime.h>

namespace {
constexpr int NNODES = 128;
constexpr int NEDGES = 1024;
constexpr int CAP    = 96;      // max edges per node per direction (mean is 8)
constexpr float PI_F = 3.14159265358979323846f;
}

// ---------------------------------------------------------------------------
// Fully fused: one block per node.
// Exploits that Ri/Ro columns are (scaled-)one-hot: edge e has one sender
// o(e) and one receiver r(e). Block n:
//   phase 1: read own Ri/Ro rows -> lists of in-edges / out-edges
//   phase 2: wave-parallel column scans -> o(e) (resp. r(e)) + column value
//   phase 3: angles M[15] via LDS atomics
//   phase 4: wave 0 simulates sub-circuit A (qubits 0..7, 256 amps),
//            wave 1 simulates sub-circuit B (qubits 8,9,10,11,13,14, 64 amps).
//            Qubit 12 is unentangled & unmeasured -> dropped.
// A bit map: reg bit0=q0, reg bit1=q1, lane bit (q-2) = qubit q (q=2..7).
// B bit map: lane bits {0..5} = qubits {8,9,10,11,13,14}.
// ---------------------------------------------------------------------------
__global__ __launch_bounds__(256)
void nodenet_fused(const float* __restrict__ X,
                   const float* __restrict__ ew,
                   const float* __restrict__ Ri,
                   const float* __restrict__ Ro,
                   const float* __restrict__ theta,
                   float* __restrict__ out)
{
    __shared__ float Xs[NNODES * 5];
    __shared__ float Mang[15];
    __shared__ int   cin, cout;
    __shared__ int   inE[CAP];  __shared__ float inW[CAP];
    __shared__ int   inO[CAP];  __shared__ float inV[CAP];
    __shared__ int   outE[CAP]; __shared__ float outW[CAP];
    __shared__ int   outR[CAP]; __shared__ float outV[CAP];

    const int n = blockIdx.x, tid = threadIdx.x;
    const int lane = tid & 63, wid = tid >> 6;

    // ---- phase 0: stage X, init angle accumulators ----
    for (int i = tid; i < NNODES * 5; i += 256) Xs[i] = X[i];
    if (tid < 10) Mang[tid] = 0.f;
    else if (tid < 15) Mang[tid] = X[n * 5 + (tid - 10)];
    if (tid == 0) { cin = 0; cout = 0; }
    __syncthreads();

    // ---- phase 1: scan own rows for incident edges ----
    #pragma unroll
    for (int j = 0; j < 4; ++j) {
        const int e = tid + j * 256;
        const float riv = Ri[n * NEDGES + e];
        const float rov = Ro[n * NEDGES + e];
        if (riv != 0.f) {
            const int idx = atomicAdd(&cin, 1);
            if (idx < CAP) { inE[idx] = e; inW[idx] = riv * ew[e]; }
        }
        if (rov != 0.f) {
            const int idx = atomicAdd(&cout, 1);
            if (idx < CAP) { outE[idx] = e; outW[idx] = rov * ew[e]; }
        }
    }
    __syncthreads();

    // ---- phase 2: column scans, one wave per edge, hit-lane writes ----
    const int ci = min(cin, CAP), co = min(cout, CAP);
    const int total = ci + co;
    for (int t = wid; t < total; t += 4) {
        const bool isIn = (t < ci);
        const int  e    = isIn ? inE[t] : outE[t - ci];
        const float* col = isIn ? Ro : Ri;     // opposite matrix's column
        const float v0 = col[lane * NEDGES + e];
        const float v1 = col[(lane + 64) * NEDGES + e];
        if (isIn) {
            if (lane == 0)  { inO[t] = 0; inV[t] = 0.f; }   // safety init
            if (v0 != 0.f)  { inO[t] = lane;      inV[t] = v0; }
            if (v1 != 0.f)  { inO[t] = lane + 64; inV[t] = v1; }
        } else {
            const int j = t - ci;
            if (lane == 0)  { outR[j] = 0; outV[j] = 0.f; }
            if (v0 != 0.f)  { outR[j] = lane;      outV[j] = v0; }
            if (v1 != 0.f)  { outR[j] = lane + 64; outV[j] = v1; }
        }
    }
    __syncthreads();

    // ---- phase 3: accumulate angles ----
    if (tid < ci) {
        const float wv = inW[tid] * inV[tid];
        const int   o  = inO[tid];
        #pragma unroll
        for (int k = 0; k < 5; ++k) atomicAdd(&Mang[k], wv * Xs[o * 5 + k]);
    } else if (tid >= 128 && tid - 128 < co) {
        const int   j  = tid - 128;
        const float wv = outW[j] * outV[j];
        const int   r  = outR[j];
        #pragma unroll
        for (int k = 0; k < 5; ++k) atomicAdd(&Mang[5 + k], wv * Xs[r * 5 + k]);
    }
    __syncthreads();
    if (wid >= 2) return;

    float c_, s_, t_, v0, v1, v2, v3;
#define CS(i)        __sincosf(0.5f * theta[i], &s_, &c_)

    if (wid == 0) {
        // ================= circuit A (qubits 0..7) =================
        float ic[8], is[8];
        #pragma unroll
        for (int q = 0; q < 8; ++q) __sincosf(0.5f * Mang[q], &is[q], &ic[q]);

        float lp = 1.f;
        #pragma unroll
        for (int q = 2; q < 8; ++q) lp *= ((lane >> (q - 2)) & 1) ? is[q] : ic[q];
        float r0 = lp * ic[0] * ic[1];
        float r1 = lp * is[0] * ic[1];
        float r2 = lp * ic[0] * is[1];
        float r3 = lp * is[0] * is[1];

#define RY_REG0      { t_ = r0; r0 = c_*t_ - s_*r1; r1 = fmaf(s_, t_, c_*r1); \
                       t_ = r2; r2 = c_*t_ - s_*r3; r3 = fmaf(s_, t_, c_*r3); }
#define RY_REG1      { t_ = r0; r0 = c_*t_ - s_*r2; r2 = fmaf(s_, t_, c_*r2); \
                       t_ = r1; r1 = c_*t_ - s_*r3; r3 = fmaf(s_, t_, c_*r3); }
#define RY_LANE_A(sh){ const float sg = ((lane >> (sh)) & 1) ? s_ : -s_;      \
                       v0 = __shfl_xor(r0, 1 << (sh), 64);                    \
                       v1 = __shfl_xor(r1, 1 << (sh), 64);                    \
                       v2 = __shfl_xor(r2, 1 << (sh), 64);                    \
                       v3 = __shfl_xor(r3, 1 << (sh), 64);                    \
                       r0 = fmaf(c_, r0, sg*v0); r1 = fmaf(c_, r1, sg*v1);    \
                       r2 = fmaf(c_, r2, sg*v2); r3 = fmaf(c_, r3, sg*v3); }
#define CX_LL_A(csh, tsh) { const bool p = (lane >> (csh)) & 1;               \
                       v0 = __shfl_xor(r0, 1 << (tsh), 64);                   \
                       v1 = __shfl_xor(r1, 1 << (tsh), 64);                   \
                       v2 = __shfl_xor(r2, 1 << (tsh), 64);                   \
                       v3 = __shfl_xor(r3, 1 << (tsh), 64);                   \
                       if (p) { r0 = v0; r1 = v1; r2 = v2; r3 = v3; } }

        CS(0);  RY_REG0;                     // R t0 q0
        CS(1);  RY_REG1;                     // R t1 q1
        t_ = r1; r1 = r3; r3 = t_;           // C(0->1): ctrl reg0, tgt reg1
        CS(2);  RY_LANE_A(0);                // R t2 q2
        CS(3);  RY_LANE_A(1);                // R t3 q3
        CX_LL_A(1, 0);                       // C(3->2)
        CS(4);  RY_LANE_A(2);                // R t4 q4
        CS(5);  RY_LANE_A(3);                // R t5 q5
        CX_LL_A(2, 3);                       // C(4->5)
        CS(6);  RY_LANE_A(4);                // R t6 q6
        CS(7);  RY_LANE_A(5);                // R t7 q7
        CX_LL_A(5, 4);                       // C(7->6)
        CS(15); RY_REG1;                     // R t15 q1
        CS(16); RY_LANE_A(0);                // R t16 q2
        r2 = __shfl_xor(r2, 1, 64);          // C(1->2): ctrl reg1, tgt lane0
        r3 = __shfl_xor(r3, 1, 64);
        CS(14); RY_LANE_A(3);                // R t14 q5
        CS(15); RY_LANE_A(4);                // R t15 q6
        CX_LL_A(4, 3);                       // C(6->5)
        CS(19); RY_LANE_A(0);                // R t19 q2
        CS(20); RY_LANE_A(3);                // R t20 q5
        CX_LL_A(0, 3);                       // C(2->5)
        CS(23); RY_LANE_A(3);                // R t23 q5
        CS(25); RY_REG0;                     // R t25 q0
        CS(26); RY_LANE_A(3);                // R t26 q5
        r1 = __shfl_xor(r1, 8, 64);          // C(0->5): ctrl reg0, tgt lane3
        r3 = __shfl_xor(r3, 8, 64);
        CS(29); RY_LANE_A(3);                // R t29 q5

        float zA = (r0*r0 + r1*r1 + r2*r2 + r3*r3) * (((lane >> 3) & 1) ? -1.f : 1.f);
        #pragma unroll
        for (int m = 1; m < 64; m <<= 1) zA += __shfl_xor(zA, m, 64);
        if (lane == 0) out[n * 2 + 0] = PI_F * (1.f - zA);
    } else {
        // ================= circuit B (qubits 8,9,10,11,13,14) =================
        float c8, s8, c9, s9, c10, s10, c11, s11, c13, s13, c14, s14;
        __sincosf(0.5f * Mang[8],  &s8,  &c8);
        __sincosf(0.5f * Mang[9],  &s9,  &c9);
        __sincosf(0.5f * Mang[10], &s10, &c10);
        __sincosf(0.5f * Mang[11], &s11, &c11);
        __sincosf(0.5f * Mang[13], &s13, &c13);
        __sincosf(0.5f * Mang[14], &s14, &c14);

        float b = ((lane >> 0) & 1) ? s8  : c8;
        b      *= ((lane >> 1) & 1) ? s9  : c9;
        b      *= ((lane >> 2) & 1) ? s10 : c10;
        b      *= ((lane >> 3) & 1) ? s11 : c11;
        b      *= ((lane >> 4) & 1) ? s13 : c13;
        b      *= ((lane >> 5) & 1) ? s14 : c14;

#define RY_B(sh)     { const float sg = ((lane >> (sh)) & 1) ? s_ : -s_;      \
                       v0 = __shfl_xor(b, 1 << (sh), 64);                     \
                       b = fmaf(c_, b, sg*v0); }
#define CX_B(csh, tsh) { v0 = __shfl_xor(b, 1 << (tsh), 64);                  \
                       if ((lane >> (csh)) & 1) b = v0; }

        CS(8);  RY_B(0);                     // R t8  q8
        CS(9);  RY_B(1);                     // R t9  q9
        CX_B(0, 1);                          // C(8->9)
        CS(10); RY_B(2);                     // R t10 q10
        CS(11); RY_B(3);                     // R t11 q11
        CX_B(3, 2);                          // C(11->10)
        CS(13); RY_B(4);                     // R t13 q13
        CX_B(0, 1);                          // C(8->9)
        CS(14); RY_B(5);                     // R t14 q14
        CS(16); RY_B(1);                     // R t16 q9
        CS(17); RY_B(2);                     // R t17 q10
        CX_B(1, 2);                          // C(9->10)
        CS(18); RY_B(4);                     // R t18 q13
        CS(19); RY_B(5);                     // R t19 q14
        CX_B(1, 2);                          // C(9->10)
        CS(21); RY_B(2);                     // R t21 q10
        CS(22); RY_B(4);                     // R t22 q13
        CX_B(4, 2);                          // C(13->10)
        CS(24); RY_B(2);                     // R t24 q10
        CS(27); RY_B(2);                     // R t27 q10
        CS(28); RY_B(5);                     // R t28 q14
        CX_B(5, 2);                          // C(14->10)
        CS(30); RY_B(2);                     // R t30 q10

        float zB = (b * b) * (((lane >> 2) & 1) ? -1.f : 1.f);
        #pragma unroll
        for (int m = 1; m < 64; m <<= 1) zB += __shfl_xor(zB, m, 64);
        if (lane == 0) out[n * 2 + 1] = PI_F * (1.f - zB);
    }
#undef CS
#undef RY_REG0
#undef RY_REG1
#undef RY_LANE_A
#undef CX_LL_A
#undef RY_B
#undef CX_B
}

extern "C" void kernel_launch(void* const* d_in, const int* in_sizes, int n_in,
                              void* d_out, int out_size, void* d_ws, size_t ws_size,
                              hipStream_t stream) {
    (void)in_sizes; (void)n_in; (void)d_ws; (void)ws_size; (void)out_size;
    const float* X     = (const float*)d_in[0];
    const float* ew    = (const float*)d_in[1];
    const float* Ri    = (const float*)d_in[2];
    const float* Ro    = (const float*)d_in[3];
    const float* theta = (const float*)d_in[4];
    float* out = (float*)d_out;

    nodenet_fused<<<NNODES, 256, 0, stream>>>(X, ew, Ri, Ro, theta, out);
}